// Round 2
// baseline (367.319 us; speedup 1.0000x reference)
//
#include <hip/hip_runtime.h>

// Reassemble overlapping patches with Fourier subpixel shift, done as two
// real circulant-matmul stages + a rank-1 correction.
//
// out[b,y,x] = sum_c (-1)^{x+y} * ( V_c[y,x] - sx_c*sy_c*Qt_c ) / M^2
//   P~[r,m]  = (-1)^{r+m} * patches[b,r,m,c]
//   U[r,x]   = sum_m P~[r,m] * px[(x-m-32) mod 128]
//   V[y,x]   = sum_r U[r,x]  * py[(y-r-32) mod 128]
//   px[t]    = sin(pi*dx) * cot(pi*(t-dx)/128)   (delta at t ≡ dx for integer dx)
//   Qt       = sum_{r,m} P~[r,m]

#define M_CANVAS 128
#define NPATCH   64
#define NCH      16
#define CG       4      // channels per workgroup -> 4 WGs per batch image

__device__ __forceinline__ int up_swz(int x) {
    // +1 float pad every 8: spreads the 16 stride-8 column starts over all 32 banks
    return x + (x >> 3);
}

__global__ __launch_bounds__(256)
void reassemble_kernel(const float* __restrict__ patches,
                       const float* __restrict__ positions,
                       float* __restrict__ out)
{
    __shared__ float sPtT[64][69];      // transposed checkerboarded patch [m][r]
    __shared__ float sU[64 * 144];      // stage-A output, row stride 144 with up_swz within row
    __shared__ float pxT2[256];         // duplicated circulant tables (avoids mod-128 in inner loops)
    __shared__ float pyT2[256];
    __shared__ float sQ[4];

    const int tid = threadIdx.x;
    const int b   = blockIdx.x >> 2;
    const int cg  = blockIdx.x & 3;

    // stage-B per-thread output tile: 8y x 8x
    const int y0 = (tid >> 4) * 8;
    const int x0 = (tid & 15) * 8;
    // stage-A mapping: 8 consecutive r, 4 strided x
    const int r0 = (tid & 7) * 8;
    const int xi = tid >> 3;            // 0..31

    float acc[8][8];
    #pragma unroll
    for (int i = 0; i < 8; ++i)
        #pragma unroll
        for (int j = 0; j < 8; ++j) acc[i][j] = 0.f;
    float Stot = 0.f;

    const float PI = 3.14159265358979323846f;

    for (int cc = 0; cc < CG; ++cc) {
        const int c = cg * CG + cc;

        __syncthreads();   // previous iteration's stage-B readers are done with sU / tables

        // ---- per-channel shift params (all threads redundantly; broadcast loads) ----
        const float dy = positions[(b * NCH + c) * 2 + 0];
        const float dx = positions[(b * NCH + c) * 2 + 1];
        // accurate sin(pi*d) via range reduction: sin(pi*(d-k)) * (-1)^k
        float kdxf = rintf(dx), kdyf = rintf(dy);
        float sx = sinf((dx - kdxf) * PI);
        if (((int)kdxf) & 1) sx = -sx;
        float sy = sinf((dy - kdyf) * PI);
        if (((int)kdyf) & 1) sy = -sy;

        // ---- build circulant tables: threads 0..127 -> px, 128..255 -> py ----
        {
            const int   t  = tid & 127;
            const float d  = (tid < 128) ? dx : dy;
            const float sd = (tid < 128) ? sx : sy;
            float u  = (float)t - d;
            float ur = u - 128.f * rintf(u * (1.f / 128.f));   // reduce: cot has period pi
            float th = ur * (PI / 128.f);                       // |th| <= pi/2, accurate
            float sth = sinf(th);
            float cth = cosf(th);
            float v;
            if (fabsf(sth) < 1e-12f)
                v = (t & 1) ? 128.f : -128.f;                   // exact integer shift: delta
            else
                v = sd * cth / sth;
            if (tid < 128) { pxT2[t] = v; pxT2[t + 128] = v; }
            else           { pyT2[t] = v; pyT2[t + 128] = v; }
        }

        // ---- load patch (checkerboard sign, transposed) + partial Q ----
        float qp = 0.f;
        {
            const int mloc  = tid & 63;          // consecutive lanes -> consecutive m (global stride 64B)
            const int rbase = tid >> 6;          // 0..3
            const float* src = patches + ((size_t)b * NPATCH * NPATCH) * NCH + c;
            #pragma unroll
            for (int i = 0; i < 16; ++i) {
                const int r = i * 4 + rbase;
                float v  = src[((size_t)r * 64 + mloc) * 16];
                float sg = ((r + mloc) & 1) ? -1.f : 1.f;
                float sv = sg * v;
                sPtT[mloc][r] = sv;
                qp += sv;
            }
        }
        #pragma unroll
        for (int off = 32; off >= 1; off >>= 1)
            qp += __shfl_down(qp, off, 64);
        if ((tid & 63) == 0) sQ[tid >> 6] = qp;

        __syncthreads();   // tables + patch + sQ visible

        const float Qt = sQ[0] + sQ[1] + sQ[2] + sQ[3];
        Stot += sx * sy * Qt;

        // ---- stage A: U[r0+i][xi+32k] = sum_m P~T[m][r0+i] * px[xi+32k-m+96] ----
        float aU[8][4];
        #pragma unroll
        for (int i = 0; i < 8; ++i)
            #pragma unroll
            for (int k = 0; k < 4; ++k) aU[i][k] = 0.f;

        for (int m = 0; m < 64; ++m) {
            float pA[8];
            #pragma unroll
            for (int i = 0; i < 8; ++i) pA[i] = sPtT[m][r0 + i];
            const int base = xi + 96 - m;        // in [33,127]
            float pX[4];
            #pragma unroll
            for (int k = 0; k < 4; ++k) pX[k] = pxT2[base + 32 * k];
            #pragma unroll
            for (int i = 0; i < 8; ++i)
                #pragma unroll
                for (int k = 0; k < 4; ++k)
                    aU[i][k] = fmaf(pA[i], pX[k], aU[i][k]);
        }

        #pragma unroll
        for (int i = 0; i < 8; ++i)
            #pragma unroll
            for (int k = 0; k < 4; ++k)
                sU[(r0 + i) * 144 + up_swz(xi + 32 * k)] = aU[i][k];

        __syncthreads();   // sU ready

        // ---- stage B: acc[i][j] += sum_r py[y0+i-r+96] * U[r][x0+j] ----
        const int ub = 9 * (x0 >> 3);            // up_swz(x0+j) = ub + j for j<8
        for (int r = 0; r < 64; ++r) {
            float U8[8];
            const float* urow = &sU[r * 144 + ub];
            #pragma unroll
            for (int j = 0; j < 8; ++j) U8[j] = urow[j];
            const int pb = y0 + 96 - r;          // in [33,216]
            float py8[8];
            #pragma unroll
            for (int i = 0; i < 8; ++i) py8[i] = pyT2[pb + i];
            #pragma unroll
            for (int i = 0; i < 8; ++i)
                #pragma unroll
                for (int j = 0; j < 8; ++j)
                    acc[i][j] = fmaf(py8[i], U8[j], acc[i][j]);
        }
    }

    // ---- epilogue: sign, rank-1 correction, scale, scatter-add ----
    const float inv = 1.f / 16384.f;             // 1/M^2
    float* ob = out + (size_t)b * M_CANVAS * M_CANVAS;
    #pragma unroll
    for (int i = 0; i < 8; ++i) {
        const int y = y0 + i;
        #pragma unroll
        for (int j = 0; j < 8; ++j) {
            const int x = x0 + j;
            const float sgn = ((x + y) & 1) ? -1.f : 1.f;
            atomicAdd(&ob[y * M_CANVAS + x], sgn * (acc[i][j] - Stot) * inv);
        }
    }
}

extern "C" void kernel_launch(void* const* d_in, const int* in_sizes, int n_in,
                              void* d_out, int out_size, void* d_ws, size_t ws_size,
                              hipStream_t stream)
{
    const float* patches   = (const float*)d_in[0];
    const float* positions = (const float*)d_in[1];
    float* out = (float*)d_out;

    const int B = in_sizes[1] / (NCH * 2);       // 128

    hipMemsetAsync(d_out, 0, (size_t)out_size * sizeof(float), stream);
    reassemble_kernel<<<dim3(B * 4), dim3(256), 0, stream>>>(patches, positions, out);
}

// Round 3
// 185.798 us; speedup vs baseline: 1.9770x; 1.9770x over previous
//
#include <hip/hip_runtime.h>

// Fourier-shift patch reassembly as two real circulant matmuls + rank-1 term.
//   out[b,y,x] = sum_c (-1)^{x+y} ( V_c[y,x] - sx sy Qt ) / M^2
//   U[r,x] = sum_m P~[r,m] px[x-m+96] ; V[y,x] = sum_r U[r,x] py[y-r+96]
// Layouts (bank-analyzed):
//   sPtT[m][r]  stride 68 : writes 2-way (bank = (l + rb) mod 32), reads 1 aligned b128/thread
//   sU[r][x]    stride 128, chunk-XOR f(r)=(r>>2)&7 : b128 writes at 8-cyc floor, reads 4-cyc
//   px/py      : sliding register windows, 1 ds_read_b32 per k-step (temp-commit kills WAR)
// Epilogue: per-WG partial canvases in d_ws + reduce kernel (no device-scope atomics).

#define NPATCH 64
#define MC     128
#define NCH    16
#define CG     2      // channels per WG -> 8 WGs per image
#define WPB    8

typedef float f32x4 __attribute__((ext_vector_type(4)));

template<bool USE_WS>
__global__ __launch_bounds__(256, 3)
void reassemble_kernel(const float* __restrict__ patches,
                       const float* __restrict__ positions,
                       float* __restrict__ dst,      // ws partials (USE_WS) or out (atomic)
                       int B)
{
    __shared__ float sPtT[64 * 68];   // [m][r]
    __shared__ float sU[64 * 128];    // [r][xor-chunked x]
    __shared__ float pxT2[256];
    __shared__ float pyT2[256];
    __shared__ float sQ[4];

    const int tid = threadIdx.x;
    int b, cg;
    if (B == 128) {  // XCD-aware: keep all 8 WGs of one image on one XCD's L2
        const int xcd  = blockIdx.x & 7;
        const int slot = blockIdx.x >> 3;        // 0..127
        b  = xcd * 16 + (slot >> 3);
        cg = slot & 7;
    } else { b = blockIdx.x >> 3; cg = blockIdx.x & 7; }

    const int l = tid & 63, w = tid >> 6;
    // stage-A map: 4 consecutive r x 8 consecutive x
    const int ga = tid & 15;          // r-quad
    const int X0 = (tid >> 4) * 8;    // x-octet base
    // stage-B map: 16 consecutive y x 4 consecutive x
    const int xg = tid & 31;          // x-quad
    const int Y0 = (tid >> 5) * 16;   // y base

    float acc[16][4];
    #pragma unroll
    for (int i = 0; i < 16; ++i)
        #pragma unroll
        for (int j = 0; j < 4; ++j) acc[i][j] = 0.f;
    float Stot = 0.f;

    const float PI = 3.14159265358979323846f;

    for (int cc = 0; cc < CG; ++cc) {
        const int c = cg * CG + cc;

        __syncthreads();   // prev channel's readers done with sU / tables / sPtT

        const float dy = positions[(b * NCH + c) * 2 + 0];
        const float dx = positions[(b * NCH + c) * 2 + 1];
        float kdxf = rintf(dx), kdyf = rintf(dy);
        float sx = sinf((dx - kdxf) * PI); if (((int)kdxf) & 1) sx = -sx;
        float sy = sinf((dy - kdyf) * PI); if (((int)kdyf) & 1) sy = -sy;

        // ---- circulant tables (threads 0..127 -> px, 128..255 -> py) ----
        {
            const int   t  = tid & 127;
            const float d  = (tid < 128) ? dx : dy;
            const float sd = (tid < 128) ? sx : sy;
            float u   = (float)t - d;
            float ur  = u - 128.f * rintf(u * (1.f / 128.f));
            float th  = ur * (PI / 128.f);
            float sth = sinf(th), cth = cosf(th);
            float v = (fabsf(sth) < 1e-12f) ? ((t & 1) ? 128.f : -128.f)
                                            : sd * cth / sth;
            if (tid < 128) { pxT2[t] = v; pxT2[t + 128] = v; }
            else           { pyT2[t] = v; pyT2[t + 128] = v; }
        }

        // ---- patch -> sPtT[m][r] (checkerboard sign) + Q partial ----
        float qp = 0.f;
        {
            const float* src = patches + ((size_t)b * 64 * 64) * 16 + c;
            #pragma unroll
            for (int k = 0; k < 16; ++k) {
                const int m = (l >> 2) + 16 * (k & 3);
                const int r = (l & 3) + 4 * (k >> 2) + 16 * w;
                float v  = src[(size_t)(r * 64 + m) * 16];
                float sv = ((r + m) & 1) ? -v : v;
                sPtT[68 * m + r] = sv;
                qp += sv;
            }
        }
        #pragma unroll
        for (int off = 32; off >= 1; off >>= 1) qp += __shfl_down(qp, off, 64);
        if (l == 0) sQ[w] = qp;

        __syncthreads();   // sPtT + tables + sQ ready

        const float Qt = sQ[0] + sQ[1] + sQ[2] + sQ[3];
        Stot += sx * sy * Qt;

        // ---- stage A: aU[i][j] = sum_m sPtT[m][4ga+i] * px[X0+j+96-m] ----
        float pw[8];
        #pragma unroll
        for (int j = 0; j < 8; ++j) pw[j] = pxT2[X0 + 96 + j];

        float aU[4][8];
        #pragma unroll
        for (int i = 0; i < 4; ++i)
            #pragma unroll
            for (int j = 0; j < 8; ++j) aU[i][j] = 0.f;

        for (int mb = 0; mb < 8; ++mb) {
            #pragma unroll
            for (int s = 0; s < 8; ++s) {
                const int m = mb * 8 + s;
                f32x4 pp = *(const f32x4*)&sPtT[68 * m + 4 * ga];
                float nxt = pxT2[X0 + 95 - m];          // window value for m+1
                #pragma unroll
                for (int i = 0; i < 4; ++i)
                    #pragma unroll
                    for (int j = 0; j < 8; ++j)
                        aU[i][j] = fmaf(pp[i], pw[(j + 8 - s) & 7], aU[i][j]);
                pw[(7 - s) & 7] = nxt;                  // slot (-(m+1)) & 7
            }
        }

        // write aU -> sU (b128, chunk-XOR by row-quad)
        #pragma unroll
        for (int i = 0; i < 4; ++i) {
            const int row = 4 * ga + i;
            #pragma unroll
            for (int q = 0; q < 2; ++q) {
                const int ch = ((X0 >> 2) + q) ^ (ga & 7);
                f32x4 v;
                v[0] = aU[i][4*q+0]; v[1] = aU[i][4*q+1];
                v[2] = aU[i][4*q+2]; v[3] = aU[i][4*q+3];
                *(f32x4*)&sU[128 * row + 4 * ch] = v;
            }
        }

        __syncthreads();   // sU ready

        // ---- stage B: acc[jy][ix] += sum_r sU[r][4xg+ix] * py[Y0+jy+96-r] ----
        float pwy[16];
        #pragma unroll
        for (int j = 0; j < 16; ++j) pwy[j] = pyT2[Y0 + 96 + j];

        for (int rb = 0; rb < 4; ++rb) {
            #pragma unroll
            for (int s = 0; s < 16; ++s) {
                const int r = rb * 16 + s;
                f32x4 u = *(const f32x4*)&sU[128 * r + 4 * (xg ^ ((r >> 2) & 7))];
                float nxt = pyT2[Y0 + 95 - r];
                #pragma unroll
                for (int jy = 0; jy < 16; ++jy) {
                    const float pv = pwy[(jy + 16 - s) & 15];
                    #pragma unroll
                    for (int ix = 0; ix < 4; ++ix)
                        acc[jy][ix] = fmaf(pv, u[ix], acc[jy][ix]);
                }
                pwy[(15 - s) & 15] = nxt;
            }
        }
    }

    // ---- epilogue: sign, rank-1 correction, scale ----
    const float inv = 1.f / 16384.f;
    if (USE_WS) {
        float* pb_ = dst + (size_t)(b * WPB + cg) * 16384;
        #pragma unroll
        for (int jy = 0; jy < 16; ++jy) {
            const int y = Y0 + jy;
            f32x4 v;
            #pragma unroll
            for (int ix = 0; ix < 4; ++ix) {
                const int x = 4 * xg + ix;
                const float sg = ((x + y) & 1) ? -1.f : 1.f;
                v[ix] = sg * (acc[jy][ix] - Stot) * inv;
            }
            *(f32x4*)&pb_[y * 128 + 4 * xg] = v;
        }
    } else {
        float* ob = dst + (size_t)b * 16384;
        #pragma unroll
        for (int jy = 0; jy < 16; ++jy) {
            const int y = Y0 + jy;
            #pragma unroll
            for (int ix = 0; ix < 4; ++ix) {
                const int x = 4 * xg + ix;
                const float sg = ((x + y) & 1) ? -1.f : 1.f;
                atomicAdd(&ob[y * 128 + x], sg * (acc[jy][ix] - Stot) * inv);
            }
        }
    }
}

__global__ __launch_bounds__(256)
void reduce_kernel(const float* __restrict__ ws, float* __restrict__ out, int B)
{
    const int t4 = blockIdx.x * 256 + threadIdx.x;
    if (t4 >= B * 4096) return;
    const int b = t4 >> 12, q = t4 & 4095;
    const f32x4* w4 = (const f32x4*)ws;
    f32x4 s = w4[((size_t)b * WPB) * 4096 + q];
    #pragma unroll
    for (int g = 1; g < WPB; ++g) {
        f32x4 v = w4[((size_t)(b * WPB + g)) * 4096 + q];
        s[0] += v[0]; s[1] += v[1]; s[2] += v[2]; s[3] += v[3];
    }
    ((f32x4*)out)[t4] = s;
}

extern "C" void kernel_launch(void* const* d_in, const int* in_sizes, int n_in,
                              void* d_out, int out_size, void* d_ws, size_t ws_size,
                              hipStream_t stream)
{
    const float* patches   = (const float*)d_in[0];
    const float* positions = (const float*)d_in[1];
    float* out = (float*)d_out;

    const int B = in_sizes[1] / (NCH * 2);              // 128
    const size_t need = (size_t)B * WPB * 16384 * sizeof(float);  // 67 MB

    if (ws_size >= need) {
        reassemble_kernel<true><<<dim3(B * WPB), dim3(256), 0, stream>>>(
            patches, positions, (float*)d_ws, B);
        reduce_kernel<<<dim3(B * 16), dim3(256), 0, stream>>>(
            (const float*)d_ws, out, B);
    } else {
        hipMemsetAsync(d_out, 0, (size_t)out_size * sizeof(float), stream);
        reassemble_kernel<false><<<dim3(B * WPB), dim3(256), 0, stream>>>(
            patches, positions, out, B);
    }
}

// Round 4
// 110.127 us; speedup vs baseline: 3.3354x; 1.6871x over previous
//
#include <hip/hip_runtime.h>

// Fourier-shift patch reassembly = two circulant matmuls + rank-1 term, on MFMA.
//   U[r,x] = sum_m P~[r,m] px[x-m+96] ;  V[y,x] = sum_r U[r,x] py[y-r+96]
//   out[b,y,x] = sum_c (-1)^{x+y} ( V - sx sy Qt ) / M^2
// Precision: split-bf16 (x = hi+lo), passes hi*hi + hi*lo + lo*hi -> ~fp32.
// Circulant operands read directly from REVERSED 8-copy-aligned kernel tables:
//   R[j] = px2[223-j]; frag = aligned b128 at copy a=(-j0)&7, slot j0+a.
// LDS: P~ [64r][64m] chunk-swz (m>>3)^(r&7); U^T [128x][64r] chunk-swz (r>>3)^sw(x).

#define NCH 16
#define CG  4
#define WPB 4

typedef __attribute__((ext_vector_type(8))) short bf16x8;
typedef __attribute__((ext_vector_type(4))) float f32x4;

__device__ __forceinline__ ushort f2bf(float x) {
    union { float f; uint u; } v; v.f = x;
    uint r = v.u + 0x7fffu + ((v.u >> 16) & 1u);
    return (ushort)(r >> 16);
}
__device__ __forceinline__ float bf2f(ushort h) {
    union { uint u; float f; } v; v.u = ((uint)h) << 16; return v.f;
}
__device__ __forceinline__ int uSw(int x) { return (x ^ (x >> 3)) & 7; }

template<bool USE_WS>
__global__ __launch_bounds__(256, 2)
void reassemble_mfma(const float* __restrict__ patches,
                     const float* __restrict__ positions,
                     float* __restrict__ dst, int B)
{
    __shared__ __align__(16) ushort sTab[2][2][8][200]; // [x/y][hi/lo][copy][slot] 12.8KB
    __shared__ __align__(16) ushort sP[2][4096];        // [hi/lo] P~ swizzled      16KB
    __shared__ __align__(16) ushort sU[2][8192];        // [hi/lo] U^T swizzled     32KB
    __shared__ float sQ[4];

    const int tid  = threadIdx.x;
    const int lane = tid & 63;
    const int wv   = tid >> 6;    // wave 0..3
    const int nn   = lane & 15;   // frag row/col
    const int hh   = lane >> 4;   // frag k-group 0..3

    int b, cg;
    if (B == 128) {  // XCD-aware: all 4 WGs of an image on one XCD's L2
        const int xcd = blockIdx.x & 7, slot = blockIdx.x >> 3;
        b = xcd * 16 + (slot >> 2); cg = slot & 3;
    } else { b = blockIdx.x >> 2; cg = blockIdx.x & 3; }

    const f32x4 zero = {0.f, 0.f, 0.f, 0.f};
    f32x4 acc[2][8];                      // stage-B: ty in {2wv,2wv+1} x 8 tx
    #pragma unroll
    for (int i = 0; i < 2; ++i)
        #pragma unroll
        for (int j = 0; j < 8; ++j) acc[i][j] = zero;
    float Stot = 0.f;

    const float PI = 3.14159265358979323846f;

    for (int cc = 0; cc < CG; ++cc) {
        const int c = cg * CG + cc;
        __syncthreads();   // prev channel's readers done with sP/sU/sTab

        const float dy = positions[(b * NCH + c) * 2 + 0];
        const float dx = positions[(b * NCH + c) * 2 + 1];
        float kdxf = rintf(dx), kdyf = rintf(dy);
        float sx = sinf((dx - kdxf) * PI); if (((int)kdxf) & 1) sx = -sx;
        float sy = sinf((dy - kdyf) * PI); if (((int)kdyf) & 1) sy = -sy;

        // ---- reversed duplicated split tables: R[j] = px2[223-j], copies a: slot j+a ----
        for (int job = tid; job < 384; job += 256) {
            const int tbl = (job >= 192) ? 1 : 0;
            const int j   = job - 192 * tbl;
            const float d  = tbl ? dy : dx;
            const float sd = tbl ? sy : sx;
            const int t = 223 - j;
            float u   = (float)t - d;
            float ur  = u - 128.f * rintf(u * (1.f / 128.f));
            float th  = ur * (PI / 128.f);
            float sth = sinf(th), cth = cosf(th);
            float v = (fabsf(sth) < 1e-12f) ? ((t & 1) ? 128.f : -128.f)
                                            : sd * cth / sth;
            const ushort hi = f2bf(v);
            const ushort lo = f2bf(v - bf2f(hi));
            #pragma unroll
            for (int a = 0; a < 8; ++a) {
                sTab[tbl][0][a][j + a] = hi;
                sTab[tbl][1][a][j + a] = lo;
            }
        }

        // ---- patch -> split-bf16 P~ staging + Q partial ----
        float qp = 0.f;
        {
            const float* src = patches + (size_t)b * 65536 + c;
            const int m0 = 2 * (lane & 31);
            const int rb = lane >> 5;
            #pragma unroll
            for (int pp = 0; pp < 8; ++pp) {
                const int r = 16 * wv + 2 * pp + rb;
                const float v0 = src[(size_t)(r * 64 + m0) * 16];
                const float v1 = src[(size_t)(r * 64 + m0 + 1) * 16];
                const int odd = (r + m0) & 1;
                const float s0 = odd ? -v0 : v0;
                const float s1 = odd ? v1 : -v1;
                qp += s0 + s1;
                const ushort h0 = f2bf(s0), h1 = f2bf(s1);
                const ushort l0 = f2bf(s0 - bf2f(h0)), l1 = f2bf(s1 - bf2f(h1));
                const int idx = r * 64 + (((m0 >> 3) ^ (r & 7)) << 3) + (m0 & 7);
                *(uint*)&sP[0][idx] = (uint)h0 | ((uint)h1 << 16);
                *(uint*)&sP[1][idx] = (uint)l0 | ((uint)l1 << 16);
            }
        }
        #pragma unroll
        for (int off = 32; off >= 1; off >>= 1) qp += __shfl_down(qp, off, 64);
        if (lane == 0) sQ[wv] = qp;

        __syncthreads();   // tables + P~ + sQ ready

        Stot += sx * sy * (sQ[0] + sQ[1] + sQ[2] + sQ[3]);

        // ---- stage A (MFMA): U-tile row = wv; 8 x-tiles; K=64 (2 ksteps) x 3 splits ----
        f32x4 accA[8];
        #pragma unroll
        for (int tx = 0; tx < 8; ++tx) accA[tx] = zero;

        #pragma unroll
        for (int ks = 0; ks < 2; ++ks) {
            const int r  = 16 * wv + nn;
            const int mc = 4 * ks + hh;
            const bf16x8 Ah = *(const bf16x8*)&sP[0][r * 64 + ((mc ^ (r & 7)) << 3)];
            const bf16x8 Al = *(const bf16x8*)&sP[1][r * 64 + ((mc ^ (r & 7)) << 3)];
            #pragma unroll
            for (int tx = 0; tx < 8; ++tx) {
                const int e0 = 16 * tx + nn + 96 - 32 * ks - 8 * hh;
                const int j0 = 223 - e0;
                const int a  = (-j0) & 7;
                const bf16x8 Bh = *(const bf16x8*)&sTab[0][0][a][j0 + a];
                const bf16x8 Bl = *(const bf16x8*)&sTab[0][1][a][j0 + a];
                accA[tx] = __builtin_amdgcn_mfma_f32_16x16x32_bf16(Ah, Bh, accA[tx], 0, 0, 0);
                accA[tx] = __builtin_amdgcn_mfma_f32_16x16x32_bf16(Ah, Bl, accA[tx], 0, 0, 0);
                accA[tx] = __builtin_amdgcn_mfma_f32_16x16x32_bf16(Al, Bh, accA[tx], 0, 0, 0);
            }
        }

        // ---- U -> split-bf16 U^T LDS (pair-packed b32, swizzled) ----
        #pragma unroll
        for (int tx = 0; tx < 8; ++tx) {
            const int x  = 16 * tx + nn;
            const int r0 = 16 * wv + 4 * hh;
            #pragma unroll
            for (int p = 0; p < 2; ++p) {
                const float v0 = accA[tx][2 * p], v1 = accA[tx][2 * p + 1];
                const ushort h0 = f2bf(v0), h1 = f2bf(v1);
                const ushort l0 = f2bf(v0 - bf2f(h0)), l1 = f2bf(v1 - bf2f(h1));
                const int rr  = r0 + 2 * p;
                const int idx = x * 64 + ((((rr >> 3) ^ uSw(x))) << 3) + (rr & 7);
                *(uint*)&sU[0][idx] = (uint)h0 | ((uint)h1 << 16);
                *(uint*)&sU[1][idx] = (uint)l0 | ((uint)l1 << 16);
            }
        }

        __syncthreads();   // U^T ready

        // ---- stage B (MFMA): wave handles ty in {2wv, 2wv+1} x 8 tx ----
        #pragma unroll
        for (int ks = 0; ks < 2; ++ks) {
            #pragma unroll
            for (int sp = 0; sp < 3; ++sp) {
                const int sa = (sp == 2) ? 1 : 0;   // Py split
                const int sb = (sp == 1) ? 1 : 0;   // U  split
                bf16x8 A0, A1;
                {
                    const int e0 = 16 * (2 * wv + 0) + nn + 96 - 32 * ks - 8 * hh;
                    const int j0 = 223 - e0, a = (-j0) & 7;
                    A0 = *(const bf16x8*)&sTab[1][sa][a][j0 + a];
                }
                {
                    const int e0 = 16 * (2 * wv + 1) + nn + 96 - 32 * ks - 8 * hh;
                    const int j0 = 223 - e0, a = (-j0) & 7;
                    A1 = *(const bf16x8*)&sTab[1][sa][a][j0 + a];
                }
                const int rc = 4 * ks + hh;
                #pragma unroll
                for (int tx = 0; tx < 8; ++tx) {
                    const int x = 16 * tx + nn;
                    const bf16x8 Bu = *(const bf16x8*)&sU[sb][x * 64 + ((rc ^ uSw(x)) << 3)];
                    acc[0][tx] = __builtin_amdgcn_mfma_f32_16x16x32_bf16(A0, Bu, acc[0][tx], 0, 0, 0);
                    acc[1][tx] = __builtin_amdgcn_mfma_f32_16x16x32_bf16(A1, Bu, acc[1][tx], 0, 0, 0);
                }
            }
        }
    }

    // ---- epilogue: sign, rank-1 correction, scale ----
    const float inv = 1.f / 16384.f;
    if (USE_WS) {
        float* pb = dst + (size_t)(b * WPB + cg) * 16384;
        #pragma unroll
        for (int tyl = 0; tyl < 2; ++tyl)
            #pragma unroll
            for (int g = 0; g < 4; ++g) {
                const int y = 16 * (2 * wv + tyl) + 4 * hh + g;
                #pragma unroll
                for (int tx = 0; tx < 8; ++tx) {
                    const int x = 16 * tx + nn;
                    const float v = (acc[tyl][tx][g] - Stot) * inv;
                    pb[y * 128 + x] = ((x + y) & 1) ? -v : v;
                }
            }
    } else {
        float* ob = dst + (size_t)b * 16384;
        #pragma unroll
        for (int tyl = 0; tyl < 2; ++tyl)
            #pragma unroll
            for (int g = 0; g < 4; ++g) {
                const int y = 16 * (2 * wv + tyl) + 4 * hh + g;
                #pragma unroll
                for (int tx = 0; tx < 8; ++tx) {
                    const int x = 16 * tx + nn;
                    const float v = (acc[tyl][tx][g] - Stot) * inv;
                    atomicAdd(&ob[y * 128 + x], ((x + y) & 1) ? -v : v);
                }
            }
    }
}

__global__ __launch_bounds__(256)
void reduce_kernel(const float* __restrict__ ws, float* __restrict__ out, int B)
{
    const int t4 = blockIdx.x * 256 + threadIdx.x;
    if (t4 >= B * 4096) return;
    const int b = t4 >> 12, q = t4 & 4095;
    const f32x4* w4 = (const f32x4*)ws;
    f32x4 s = w4[(size_t)(b * WPB) * 4096 + q];
    #pragma unroll
    for (int g = 1; g < WPB; ++g) {
        f32x4 v = w4[(size_t)(b * WPB + g) * 4096 + q];
        s[0] += v[0]; s[1] += v[1]; s[2] += v[2]; s[3] += v[3];
    }
    ((f32x4*)out)[t4] = s;
}

extern "C" void kernel_launch(void* const* d_in, const int* in_sizes, int n_in,
                              void* d_out, int out_size, void* d_ws, size_t ws_size,
                              hipStream_t stream)
{
    const float* patches   = (const float*)d_in[0];
    const float* positions = (const float*)d_in[1];
    float* out = (float*)d_out;

    const int B = in_sizes[1] / (NCH * 2);                        // 128
    const size_t need = (size_t)B * WPB * 16384 * sizeof(float);  // 33.5 MB

    if (ws_size >= need) {
        reassemble_mfma<true><<<dim3(B * 4), dim3(256), 0, stream>>>(
            patches, positions, (float*)d_ws, B);
        reduce_kernel<<<dim3((B * 4096 + 255) / 256), dim3(256), 0, stream>>>(
            (const float*)d_ws, out, B);
    } else {
        hipMemsetAsync(d_out, 0, (size_t)out_size * sizeof(float), stream);
        reassemble_mfma<false><<<dim3(B * 4), dim3(256), 0, stream>>>(
            patches, positions, out, B);
    }
}